// Round 7
// baseline (47.791 us; speedup 1.0000x reference)
//
#include <hip/hip_runtime.h>

namespace {
constexpr int Wd = 160, Hd = 192, Dd = 160, Bd = 2;
constexpr int HW = Hd * Wd;
constexpr int THREADS = 256;               // 4 waves
constexpr int ROWS_OUT = 6;                // output rows per block
constexpr int ROWS_LDS = 8;                // staged rows incl. h-halo
constexpr int RS = 164;                    // x row stride (floats)
constexpr int HS = 42;                     // halo array row stride
constexpr int STRIPS = Wd / 4;             // 40
constexpr int CTHREADS = ROWS_OUT * STRIPS;   // 240 compute threads
constexpr int SLOTS = 2 * ROWS_LDS * STRIPS;  // 640 staging tasks
constexpr int DCHUNK = 10;
constexpr int NCHUNK = Dd / DCHUNK;        // 16
constexpr int RGROUPS = Hd / ROWS_OUT;     // 32  -> grid 1024 = 4 blocks/CU
constexpr float EPS = 1e-8f;
}

__global__ __launch_bounds__(THREADS) void sobel_loss_kernel(
    const float* __restrict__ pred, const float* __restrict__ targ,
    float* __restrict__ out) {
  // double-buffered: [buf][tensor][row][*]
  __shared__ float xbuf[2][2][ROWS_LDS][RS];   // 21.0 KB
  __shared__ float xlh[2][2][ROWS_LDS][HS];    // 5.4 KB  xlh[b][t][r][s] = x[4s-1]
  __shared__ float xrh[2][2][ROWS_LDS][HS];    // 5.4 KB  xrh[b][t][r][s] = x[4s+4]
  const int tid = threadIdx.x;
  const int h0 = blockIdx.x * ROWS_OUT;
  const int d0 = blockIdx.y * DCHUNK;
  const size_t volOff = (size_t)blockIdx.z * Dd * HW;
  const float* pb = pred + volOff;
  const float* tb = targ + volOff;

  // zero boundary halo columns in BOTH buffers once (never written by staging)
  if (tid < 32) {
    const int b = tid & 1, t_ = (tid >> 1) & 1, r8 = (tid >> 2) & 7;
    xlh[b][t_][r8][0] = 0.f;
    xrh[b][t_][r8][STRIPS - 1] = 0.f;
  }

  // ---- staging task decode (2.5 tasks/thread); float4-ONLY global loads ----
  const float* gs[3];
  float* dst0[3];
  float* xlp0[3];
  float* xrp0[3];
  bool rok[3], sok[3];
#pragma unroll
  for (int u = 0; u < 3; ++u) {
    const int i = tid + 256 * u;
    const bool ok = (i < SLOTS);
    const int ic = ok ? i : 0;
    const int t_ = ic >= SLOTS / 2;
    const int idx = ic - (t_ ? SLOTS / 2 : 0);
    const int r8 = idx / STRIPS, s = idx - r8 * STRIPS;
    const int hh = h0 - 1 + r8;
    const bool rv = ok && ((unsigned)hh < (unsigned)Hd);
    rok[u] = rv;
    sok[u] = ok;
    gs[u] = (t_ ? tb : pb) + (size_t)(rv ? hh : 0) * Wd + s * 4;
    dst0[u] = &xbuf[0][t_][r8][s * 4];
    xlp0[u] = &xlh[0][t_][r8][s + 1];
    xrp0[u] = &xrh[0][t_][r8][(s == 0) ? (HS - 1) : (s - 1)];  // dummy col for s==0
  }
  constexpr int XSTRIDE = 2 * ROWS_LDS * RS;   // floats between buffers
  constexpr int HSTRIDE = 2 * ROWS_LDS * HS;

  float4 rg[3];
  auto GLOAD = [&](int dsl) {            // issue 3 coalesced float4 loads
    const bool dok = (unsigned)dsl < (unsigned)Dd;
    const size_t so = (size_t)dsl * HW;
#pragma unroll
    for (int u = 0; u < 3; ++u) {
      float4 v = make_float4(0.f, 0.f, 0.f, 0.f);
      if (dok && rok[u]) v = *reinterpret_cast<const float4*>(gs[u] + so);
      rg[u] = v;
    }
  };
  auto DSW = [&](int b) {                // consume rg: write x + halo dups to buf b
#pragma unroll
    for (int u = 0; u < 3; ++u) {
      if (sok[u]) {
        *reinterpret_cast<float4*>(dst0[u] + b * XSTRIDE) = rg[u];
        *(xlp0[u] + b * HSTRIDE) = rg[u].w;
        *(xrp0[u] + b * HSTRIDE) = rg[u].x;
      }
    }
  };

  // ---- compute-thread decode ----
  const int cr = tid / STRIPS;           // 0..5 for tid<240
  const int cs = tid - cr * STRIPS;
  const int w0 = cs * 4;
  const bool is_c = (tid < CTHREADS);

  // rolling state [slot][tensor]
  float A[3][2][4], B[3][2][4], C[3][2][4];

  auto ABC = [&](int slot, int b) {
#pragma unroll
    for (int t_ = 0; t_ < 2; ++t_) {
      float sw[3][4], dwv[3][4];
#pragma unroll
      for (int rr = 0; rr < 3; ++rr) {
        const float4 m = *reinterpret_cast<const float4*>(&xbuf[b][t_][cr + rr][w0]);
        const float xl = xlh[b][t_][cr + rr][cs];
        const float xr = xrh[b][t_][cr + rr][cs];
        const float x[6] = {xl, m.x, m.y, m.z, m.w, xr};
#pragma unroll
        for (int j = 0; j < 4; ++j) {
          sw[rr][j]  = x[j] + 2.f * x[j + 1] + x[j + 2];
          dwv[rr][j] = x[j + 2] - x[j];
        }
      }
#pragma unroll
      for (int j = 0; j < 4; ++j) {
        A[slot][t_][j] = sw[0][j] + 2.f * sw[1][j] + sw[2][j];
        B[slot][t_][j] = dwv[0][j] + 2.f * dwv[1][j] + dwv[2][j];
        C[slot][t_][j] = sw[2][j] - sw[0][j];
      }
    }
  };

  float acc = 0.f;

  // ---- prologue ----
  GLOAD(d0 - 1);
  DSW(0); GLOAD(d0);                     // buf0 <- slice d0-1
  __syncthreads();
  DSW(1); GLOAD(d0 + 1);                 // buf1 <- slice d0
  if (is_c) ABC(0, 0);                   // slot0 <- slice d0-1
  __syncthreads();

  // ---- main: iter k stages slice d0+k+1, builds state for slice d0+k,
  //      outputs slice d0+k-1. ONE barrier per iteration. ----
#pragma unroll
  for (int k = 0; k <= DCHUNK; ++k) {
    if (k <= DCHUNK - 1) DSW(k & 1);             // buf[k&1] <- slice d0+k+1
    if (k <= DCHUNK - 2) GLOAD(d0 + k + 2);      // rg <- slice d0+k+2
    if (is_c) {
      ABC((k + 1) % 3, (k + 1) & 1);             // state <- slice d0+k
      if (k >= 1) {
        const int i0 = (k + 2) % 3, i1 = k % 3, i2 = (k + 1) % 3;
#pragma unroll
        for (int j = 0; j < 4; ++j) {
          float gx = B[i0][0][j] + 2.f * B[i1][0][j] + B[i2][0][j];
          float gy = C[i0][0][j] + 2.f * C[i1][0][j] + C[i2][0][j];
          float gz = A[i2][0][j] - A[i0][0][j];
          const float pm = sqrtf(fmaf(gx, gx, fmaf(gy, gy, fmaf(gz, gz, EPS))));
          gx = B[i0][1][j] + 2.f * B[i1][1][j] + B[i2][1][j];
          gy = C[i0][1][j] + 2.f * C[i1][1][j] + C[i2][1][j];
          gz = A[i2][1][j] - A[i0][1][j];
          const float tm = sqrtf(fmaf(gx, gx, fmaf(gy, gy, fmaf(gz, gz, EPS))));
          acc += fabsf(pm - tm);
        }
      }
    }
    if (k <= DCHUNK - 1) __syncthreads();
  }

  // ---- reduction: wave shfl -> LDS -> one atomic per block ----
  float sred = acc;
#pragma unroll
  for (int off = 32; off > 0; off >>= 1) sred += __shfl_down(sred, off, 64);
  __shared__ float wsum[THREADS / 64];
  const int lane = tid & 63;
  const int wid = tid >> 6;
  if (lane == 0) wsum[wid] = sred;
  __syncthreads();
  if (tid == 0) {
    float t = 0.f;
#pragma unroll
    for (int i = 0; i < THREADS / 64; ++i) t += wsum[i];
    atomicAdd(out, t * (1.0f / (float)((size_t)Bd * Dd * Hd * Wd)));
  }
}

extern "C" void kernel_launch(void* const* d_in, const int* in_sizes, int n_in,
                              void* d_out, int out_size, void* d_ws, size_t ws_size,
                              hipStream_t stream) {
  const float* pred = (const float*)d_in[0];
  const float* targ = (const float*)d_in[1];
  float* out = (float*)d_out;
  (void)in_sizes; (void)n_in; (void)out_size; (void)d_ws; (void)ws_size;

  hipMemsetAsync(out, 0, sizeof(float), stream);
  dim3 grid(RGROUPS, NCHUNK, Bd);
  sobel_loss_kernel<<<grid, THREADS, 0, stream>>>(pred, targ, out);
}